// Round 17
// baseline (67.113 us; speedup 1.0000x reference)
//
#include <hip/hip_runtime.h>
#include <hip/hip_bf16.h>
#include <stdint.h>

// Problem constants
#define N_ROWS 16384
#define C_ROWS 1000
#define C_PAD  1024
#define D_DIM  1024

#define BM 128
#define BN 128
#define BK 32
#define KSTEPS (D_DIM / BK)        // 32
#define TILE_ELEMS (BM * BK)       // 4096 elems = 8 KiB per K-step image

typedef __attribute__((ext_vector_type(8))) short    bf16x8;
typedef __attribute__((ext_vector_type(4))) float    f32x4;
typedef __attribute__((ext_vector_type(4))) uint32_t u32x4;

// fp32 -> bf16 with round-half-up bias (validated: absmax 16.0 vs thr 50.88)
__device__ __forceinline__ uint32_t pk2bf(float lo, float hi) {
    union { float f; uint32_t u; } a, b;
    a.f = lo; b.f = hi;
    uint32_t l = (a.u + 0x8000u) >> 16;
    uint32_t h = (b.u + 0x8000u) >> 16;
    return l | (h << 16);
}

// async global->LDS, 16 bytes per lane. LDS dest = uniform base + lane*16 (HW).
__device__ __forceinline__ void gl_lds16(const uint16_t* g, uint16_t* l) {
    __builtin_amdgcn_global_load_lds(
        (const __attribute__((address_space(1))) void*)g,
        (__attribute__((address_space(3))) void*)l,
        16, 0, 0);
}

// ---------------- pre-pass: fp32 -> bf16 TILED convert + row sq-norm --------
// Tiled layout (validated r10/r16): elem (r,k) ->
//   [(r/128)*KSTEPS + k/32]*4096 + ((k%32)/8)*128*8 + (r%128)*8 + k%8
__device__ __forceinline__ void conv_row(const float* __restrict__ x,
                                         uint16_t* __restrict__ xt,
                                         float* __restrict__ norms,
                                         int wid, int lane, bool valid) {
    const int tile = wid >> 7;
    const int row  = wid & 127;
    uint16_t* tbase = xt + (size_t)tile * KSTEPS * TILE_ELEMS;
    const int kslot = lane & 3;
    const int cellb = (kslot * 128 + row) * 8;
    if (valid) {
        const f32x4* rp = (const f32x4*)(x + (size_t)wid * D_DIM);
        float s = 0.f;
#pragma unroll
        for (int i = 0; i < 2; ++i) {
            f32x4 v0 = rp[i * 128 + lane * 2];
            f32x4 v1 = rp[i * 128 + lane * 2 + 1];
            s += v0[0]*v0[0] + v0[1]*v0[1] + v0[2]*v0[2] + v0[3]*v0[3]
               + v1[0]*v1[0] + v1[1]*v1[1] + v1[2]*v1[2] + v1[3]*v1[3];
            u32x4 p;
            p[0] = pk2bf(v0[0], v0[1]); p[1] = pk2bf(v0[2], v0[3]);
            p[2] = pk2bf(v1[0], v1[1]); p[3] = pk2bf(v1[2], v1[3]);
            const int t = i * 16 + (lane >> 2);
            *(u32x4*)(tbase + (size_t)t * TILE_ELEMS + cellb) = p;
        }
#pragma unroll
        for (int off = 32; off > 0; off >>= 1) s += __shfl_down(s, off, 64);
        if (lane == 0) norms[wid] = s;
    } else {
        u32x4 z = {0, 0, 0, 0};
#pragma unroll
        for (int i = 0; i < 2; ++i) {
            const int t = i * 16 + (lane >> 2);
            *(u32x4*)(tbase + (size_t)t * TILE_ELEMS + cellb) = z;
        }
        if (lane == 0) norms[wid] = 0.f;
    }
}

// single dispatch for both inputs: rows [0,16384) = E, [16384,16384+1024) = C
__global__ void convert_norm_both(const float* __restrict__ E,
                                  uint16_t* __restrict__ Et,
                                  float* __restrict__ xn,
                                  const float* __restrict__ Cc,
                                  uint16_t* __restrict__ Ct,
                                  float* __restrict__ yn) {
    int wid  = (blockIdx.x * blockDim.x + threadIdx.x) >> 6;
    int lane = threadIdx.x & 63;
    if (wid < N_ROWS) {
        conv_row(E, Et, xn, wid, lane, true);
    } else {
        int w2 = wid - N_ROWS;                 // 0..1023
        conv_row(Cc, Ct, yn, w2, lane, w2 < C_ROWS);
    }
}

// ---------------- main GEMM: r16 validated K-loop + coalesced epilogue ------
// 128x128, BK=32, dbuf, linear gload_lds from pre-tiled source, conflict-free
// ds_read. launch_bounds(256,5): 5 blocks/CU (LDS 5*32KB = 160KB exact).
__global__ __launch_bounds__(256, 5)
void dist_gemm2(const uint16_t* __restrict__ At,
                const uint16_t* __restrict__ Bt,
                const float* __restrict__ xn,
                const float* __restrict__ yn,
                float* __restrict__ out) {
    __shared__ uint16_t As[2][TILE_ELEMS];   // 2 x 8 KiB (reused as Cs after)
    __shared__ uint16_t Bs[2][TILE_ELEMS];   // 2 x 8 KiB

    const int tid  = threadIdx.x;
    const int lane = tid & 63;
    const int wid  = tid >> 6;
    const int wm   = wid >> 1;
    const int wn   = wid & 1;

    const int rowTile = blockIdx.x;   // 0..127 ; bid%8 == rowTile%8 -> XCD reuse
    const int colTile = blockIdx.y;   // 0..7

    const uint16_t* Abase = At + (size_t)rowTile * KSTEPS * TILE_ELEMS;
    const uint16_t* Bbase = Bt + (size_t)colTile * KSTEPS * TILE_ELEMS;

    const int off0 = tid * 8;          // elems (16B per thread)
    const int off1 = 2048 + tid * 8;   // second 4KB half

    const int fA = ((lane >> 4) * 128 + wm * 64 + (lane & 15)) * 8;
    const int fB = ((lane >> 4) * 128 + wn * 64 + (lane & 15)) * 8;

    f32x4 acc[4][4];
#pragma unroll
    for (int m = 0; m < 4; ++m)
#pragma unroll
        for (int n = 0; n < 4; ++n) acc[m][n] = (f32x4)(0.f);

#define STAGE(buf, t)                                               \
    do {                                                            \
        const uint16_t* ga = Abase + (size_t)(t) * TILE_ELEMS;      \
        const uint16_t* gb = Bbase + (size_t)(t) * TILE_ELEMS;      \
        gl_lds16(ga + off0, &As[buf][off0]);                        \
        gl_lds16(ga + off1, &As[buf][off1]);                        \
        gl_lds16(gb + off0, &Bs[buf][off0]);                        \
        gl_lds16(gb + off1, &Bs[buf][off1]);                        \
    } while (0)

    STAGE(0, 0);
    __syncthreads();

    int cur = 0;
    for (int t = 0; t < KSTEPS; ++t) {
        if (t + 1 < KSTEPS) STAGE(cur ^ 1, t + 1);
        bf16x8 ar[4], br[4];
#pragma unroll
        for (int m = 0; m < 4; ++m) ar[m] = *(const bf16x8*)&As[cur][fA + m * 16 * 8];
#pragma unroll
        for (int n = 0; n < 4; ++n) br[n] = *(const bf16x8*)&Bs[cur][fB + n * 16 * 8];
#pragma unroll
        for (int m = 0; m < 4; ++m)
#pragma unroll
            for (int n = 0; n < 4; ++n)
                acc[m][n] = __builtin_amdgcn_mfma_f32_16x16x32_bf16(
                    ar[m], br[n], acc[m][n], 0, 0, 0);
        __syncthreads();
        cur ^= 1;
    }
#undef STAGE

    // ---- coalesced epilogue: 8 passes x 16 rows through LDS (r16, +9us) ----
    float* Cs = (float*)&As[0][0];
    const int mrow = (lane >> 4) * 4;               // 0,4,8,12
    const int ccol = wn * 64 + (lane & 15);         // col base within tile
    const int srow = tid >> 4;                      // 0..15 (stream row)
    const int scol = (tid & 15) * 4;                // 0..60 (stream col base)

#pragma unroll
    for (int p = 0; p < 8; ++p) {
        __syncthreads();                            // Cs free
        if (wm == (p >> 2)) {
            const int m = p & 3;                    // compile-time (unrolled)
#pragma unroll
            for (int n = 0; n < 4; ++n)
#pragma unroll
                for (int r = 0; r < 4; ++r)
                    Cs[(mrow + r) * 132 + ccol + n * 16] = acc[m][n][r];
        }
        __syncthreads();                            // slab staged
        const int grow = rowTile * BM + p * 16 + srow;
        const float xr = xn[grow];
        float* orow = out + (size_t)grow * C_ROWS;
#pragma unroll
        for (int s = 0; s < 2; ++s) {
            const int c  = scol + s * 64;           // col in tile
            const int gc = colTile * BN + c;
            f32x4 d = *(f32x4*)&Cs[srow * 132 + c];
            f32x4 y4 = *(const f32x4*)&yn[gc];
            f32x4 v;
#pragma unroll
            for (int j = 0; j < 4; ++j)
                v[j] = fmaxf(xr + y4[j] - 2.0f * d[j], 0.f);
            if (gc + 3 < C_ROWS) {
                *(f32x4*)&orow[gc] = v;
            } else {
#pragma unroll
                for (int j = 0; j < 4; ++j)
                    if (gc + j < C_ROWS) orow[gc + j] = v[j];
            }
        }
    }
}

// ---------------- fallback path (round-7 validated) if ws is too small ------
__global__ void row_norms_kernel(const float* __restrict__ x,
                                 float* __restrict__ out,
                                 int rows, int pad_rows) {
    int gid  = blockIdx.x * blockDim.x + threadIdx.x;
    int wid  = gid >> 6;
    int lane = threadIdx.x & 63;
    if (wid >= pad_rows) return;
    float s = 0.f;
    if (wid < rows) {
        const f32x4* rp = (const f32x4*)(x + (size_t)wid * D_DIM);
#pragma unroll
        for (int r = 0; r < D_DIM / 256; ++r) {
            f32x4 v = rp[r * 64 + lane];
            s += v[0]*v[0] + v[1]*v[1] + v[2]*v[2] + v[3]*v[3];
        }
    }
#pragma unroll
    for (int off = 32; off > 0; off >>= 1) s += __shfl_down(s, off, 64);
    if (lane == 0) out[wid] = s;
}

__global__ __launch_bounds__(256, 2)
void dist_gemm_kernel(const float* __restrict__ E,
                      const float* __restrict__ Cc,
                      const float* __restrict__ xn,
                      const float* __restrict__ yn,
                      float* __restrict__ out) {
    __shared__ uint16_t As[4 * 128 * 8];
    __shared__ uint16_t Bs[4 * 128 * 8];
    const int tid  = threadIdx.x;
    const int lane = tid & 63;
    const int wid  = tid >> 6;
    const int wm   = wid >> 1;
    const int wn   = wid & 1;
    const int rowTile = blockIdx.y;
    const int colTile = blockIdx.x;
    const int srow = tid & 127;
    const int sp   = tid >> 7;
    const int ga = rowTile * 128 + srow;
    const int gb = colTile * 128 + srow;
    const float* Arow = E  + (size_t)ga * D_DIM + sp * 16;
    const float* Brow = Cc + (size_t)gb * D_DIM + sp * 16;
    const bool bvalid = (gb < C_ROWS);
    f32x4 acc[4][4];
#pragma unroll
    for (int m = 0; m < 4; ++m)
#pragma unroll
        for (int n = 0; n < 4; ++n) acc[m][n] = (f32x4)(0.f);
    const int fragA_base = (((lane >> 4) * 128) + wm * 64 + (lane & 15)) * 8;
    const int fragB_base = (((lane >> 4) * 128) + wn * 64 + (lane & 15)) * 8;
    const int stA0 = ((sp * 2) * 128 + srow) * 8;
    const int stA1 = ((sp * 2 + 1) * 128 + srow) * 8;
    for (int k0 = 0; k0 < D_DIM; k0 += 32) {
        f32x4 a0 = *(const f32x4*)(Arow + k0);
        f32x4 a1 = *(const f32x4*)(Arow + k0 + 4);
        f32x4 a2 = *(const f32x4*)(Arow + k0 + 8);
        f32x4 a3 = *(const f32x4*)(Arow + k0 + 12);
        f32x4 b0 = (f32x4)(0.f), b1 = (f32x4)(0.f),
              b2 = (f32x4)(0.f), b3 = (f32x4)(0.f);
        if (bvalid) {
            b0 = *(const f32x4*)(Brow + k0);
            b1 = *(const f32x4*)(Brow + k0 + 4);
            b2 = *(const f32x4*)(Brow + k0 + 8);
            b3 = *(const f32x4*)(Brow + k0 + 12);
        }
        u32x4 pa01, pa23, pb01, pb23;
        pa01[0] = pk2bf(a0[0], a0[1]); pa01[1] = pk2bf(a0[2], a0[3]);
        pa01[2] = pk2bf(a1[0], a1[1]); pa01[3] = pk2bf(a1[2], a1[3]);
        pa23[0] = pk2bf(a2[0], a2[1]); pa23[1] = pk2bf(a2[2], a2[3]);
        pa23[2] = pk2bf(a3[0], a3[1]); pa23[3] = pk2bf(a3[2], a3[3]);
        pb01[0] = pk2bf(b0[0], b0[1]); pb01[1] = pk2bf(b0[2], b0[3]);
        pb01[2] = pk2bf(b1[0], b1[1]); pb01[3] = pk2bf(b1[2], b1[3]);
        pb23[0] = pk2bf(b2[0], b2[1]); pb23[1] = pk2bf(b2[2], b2[3]);
        pb23[2] = pk2bf(b3[0], b3[1]); pb23[3] = pk2bf(b3[2], b3[3]);
        __syncthreads();
        *(u32x4*)&As[stA0] = pa01;
        *(u32x4*)&As[stA1] = pa23;
        *(u32x4*)&Bs[stA0] = pb01;
        *(u32x4*)&Bs[stA1] = pb23;
        __syncthreads();
        bf16x8 ar[4], br[4];
#pragma unroll
        for (int m = 0; m < 4; ++m) ar[m] = *(const bf16x8*)&As[fragA_base + m * 16 * 8];
#pragma unroll
        for (int n = 0; n < 4; ++n) br[n] = *(const bf16x8*)&Bs[fragB_base + n * 16 * 8];
#pragma unroll
        for (int m = 0; m < 4; ++m)
#pragma unroll
            for (int n = 0; n < 4; ++n)
                acc[m][n] = __builtin_amdgcn_mfma_f32_16x16x32_bf16(
                    ar[m], br[n], acc[m][n], 0, 0, 0);
    }
    const int orow0 = rowTile * 128 + wm * 64 + ((lane >> 4) * 4);
    const int ocol0 = colTile * 128 + wn * 64 + (lane & 15);
#pragma unroll
    for (int n = 0; n < 4; ++n) {
        int gc = ocol0 + n * 16;
        if (gc >= C_ROWS) continue;
        float ynv = yn[gc];
#pragma unroll
        for (int m = 0; m < 4; ++m) {
            int gr = orow0 + m * 16;
#pragma unroll
            for (int r = 0; r < 4; ++r) {
                float v = xn[gr + r] + ynv - 2.0f * acc[m][n][r];
                out[(size_t)(gr + r) * C_ROWS + gc] = fmaxf(v, 0.f);
            }
        }
    }
}

extern "C" void kernel_launch(void* const* d_in, const int* in_sizes, int n_in,
                              void* d_out, int out_size, void* d_ws, size_t ws_size,
                              hipStream_t stream) {
    const float* E  = (const float*)d_in[0];   // [16384, 1024]
    const float* Cc = (const float*)d_in[1];   // [1000, 1024]
    float* out = (float*)d_out;                // [16384, 1000]

    // ws layout: Et 32MB | Ct 2MB | xn 64KB | yn 4KB  (tiled bf16 images)
    uint16_t* Et = (uint16_t*)d_ws;
    uint16_t* Ct = Et + (size_t)N_ROWS * D_DIM;
    float*    xn = (float*)(Ct + (size_t)C_PAD * D_DIM);
    float*    yn = xn + N_ROWS;
    size_t need = (size_t)((char*)(yn + C_PAD) - (char*)d_ws);

    if (ws_size >= need) {
        convert_norm_both<<<(N_ROWS + C_PAD) / 4, 256, 0, stream>>>(
            E, Et, xn, Cc, Ct, yn);
        dim3 grid(N_ROWS / BM, C_PAD / BN);    // (128, 8)
        dist_gemm2<<<grid, 256, 0, stream>>>(Et, Ct, xn, yn, out);
    } else {
        // fallback: round-7 validated path (needs only ~68 KB ws)
        float* fxn = (float*)d_ws;
        float* fyn = fxn + N_ROWS;
        row_norms_kernel<<<N_ROWS / 4, 256, 0, stream>>>(E,  fxn, N_ROWS, N_ROWS);
        row_norms_kernel<<<C_PAD  / 4, 256, 0, stream>>>(Cc, fyn, C_ROWS, C_PAD);
        dim3 grid(C_PAD / 128, N_ROWS / 128);
        dist_gemm_kernel<<<grid, 256, 0, stream>>>(E, Cc, fxn, fyn, out);
    }
}

// Round 18
// 64.880 us; speedup vs baseline: 1.0344x; 1.0344x over previous
//
#include <hip/hip_runtime.h>
#include <hip/hip_bf16.h>
#include <stdint.h>

// Problem constants
#define N_ROWS 16384
#define C_ROWS 1000
#define C_PAD  1024
#define D_DIM  1024

#define BM 128
#define BN 128
#define BK 32
#define KSTEPS (D_DIM / BK)        // 32
#define TILE_ELEMS (BM * BK)       // 4096 elems = 8 KiB per K-step image

typedef __attribute__((ext_vector_type(8))) short    bf16x8;
typedef __attribute__((ext_vector_type(4))) float    f32x4;
typedef __attribute__((ext_vector_type(4))) uint32_t u32x4;

// fp32 -> bf16 with round-half-up bias (validated: absmax 16.0 vs thr 50.88)
__device__ __forceinline__ uint32_t pk2bf(float lo, float hi) {
    union { float f; uint32_t u; } a, b;
    a.f = lo; b.f = hi;
    uint32_t l = (a.u + 0x8000u) >> 16;
    uint32_t h = (b.u + 0x8000u) >> 16;
    return l | (h << 16);
}

// async global->LDS, 16 bytes per lane. LDS dest = uniform base + lane*16 (HW).
__device__ __forceinline__ void gl_lds16(const uint16_t* g, uint16_t* l) {
    __builtin_amdgcn_global_load_lds(
        (const __attribute__((address_space(1))) void*)g,
        (__attribute__((address_space(3))) void*)l,
        16, 0, 0);
}

// ---------------- pre-pass: fp32 -> bf16 TILED convert + row sq-norm --------
// Tiled layout (validated r10/r16): elem (r,k) ->
//   [(r/128)*KSTEPS + k/32]*4096 + ((k%32)/8)*128*8 + (r%128)*8 + k%8
__device__ __forceinline__ void conv_row(const float* __restrict__ x,
                                         uint16_t* __restrict__ xt,
                                         float* __restrict__ norms,
                                         int wid, int lane, bool valid) {
    const int tile = wid >> 7;
    const int row  = wid & 127;
    uint16_t* tbase = xt + (size_t)tile * KSTEPS * TILE_ELEMS;
    const int kslot = lane & 3;
    const int cellb = (kslot * 128 + row) * 8;
    if (valid) {
        const f32x4* rp = (const f32x4*)(x + (size_t)wid * D_DIM);
        float s = 0.f;
#pragma unroll
        for (int i = 0; i < 2; ++i) {
            f32x4 v0 = rp[i * 128 + lane * 2];
            f32x4 v1 = rp[i * 128 + lane * 2 + 1];
            s += v0[0]*v0[0] + v0[1]*v0[1] + v0[2]*v0[2] + v0[3]*v0[3]
               + v1[0]*v1[0] + v1[1]*v1[1] + v1[2]*v1[2] + v1[3]*v1[3];
            u32x4 p;
            p[0] = pk2bf(v0[0], v0[1]); p[1] = pk2bf(v0[2], v0[3]);
            p[2] = pk2bf(v1[0], v1[1]); p[3] = pk2bf(v1[2], v1[3]);
            const int t = i * 16 + (lane >> 2);
            *(u32x4*)(tbase + (size_t)t * TILE_ELEMS + cellb) = p;
        }
#pragma unroll
        for (int off = 32; off > 0; off >>= 1) s += __shfl_down(s, off, 64);
        if (lane == 0) norms[wid] = s;
    } else {
        u32x4 z = {0, 0, 0, 0};
#pragma unroll
        for (int i = 0; i < 2; ++i) {
            const int t = i * 16 + (lane >> 2);
            *(u32x4*)(tbase + (size_t)t * TILE_ELEMS + cellb) = z;
        }
        if (lane == 0) norms[wid] = 0.f;
    }
}

// single dispatch for both inputs: rows [0,16384) = E, [16384,16384+1024) = C
__global__ void convert_norm_both(const float* __restrict__ E,
                                  uint16_t* __restrict__ Et,
                                  float* __restrict__ xn,
                                  const float* __restrict__ Cc,
                                  uint16_t* __restrict__ Ct,
                                  float* __restrict__ yn) {
    int wid  = (blockIdx.x * blockDim.x + threadIdx.x) >> 6;
    int lane = threadIdx.x & 63;
    if (wid < N_ROWS) {
        conv_row(E, Et, xn, wid, lane, true);
    } else {
        int w2 = wid - N_ROWS;                 // 0..1023
        conv_row(Cc, Ct, yn, w2, lane, w2 < C_ROWS);
    }
}

// ---------------- main GEMM: r16 validated K-loop + coalesced epilogue ------
// 128x128, BK=32, dbuf, linear gload_lds from pre-tiled source, conflict-free
// ds_read. launch_bounds(256,4): the r16-validated 51us configuration
// ((256,5) regressed GEMM ~10% in r17 by capping VGPR 52->48).
__global__ __launch_bounds__(256, 4)
void dist_gemm2(const uint16_t* __restrict__ At,
                const uint16_t* __restrict__ Bt,
                const float* __restrict__ xn,
                const float* __restrict__ yn,
                float* __restrict__ out) {
    __shared__ uint16_t As[2][TILE_ELEMS];   // 2 x 8 KiB (reused as Cs after)
    __shared__ uint16_t Bs[2][TILE_ELEMS];   // 2 x 8 KiB

    const int tid  = threadIdx.x;
    const int lane = tid & 63;
    const int wid  = tid >> 6;
    const int wm   = wid >> 1;
    const int wn   = wid & 1;

    const int rowTile = blockIdx.x;   // 0..127 ; bid%8 == rowTile%8 -> XCD reuse
    const int colTile = blockIdx.y;   // 0..7

    const uint16_t* Abase = At + (size_t)rowTile * KSTEPS * TILE_ELEMS;
    const uint16_t* Bbase = Bt + (size_t)colTile * KSTEPS * TILE_ELEMS;

    const int off0 = tid * 8;          // elems (16B per thread)
    const int off1 = 2048 + tid * 8;   // second 4KB half

    const int fA = ((lane >> 4) * 128 + wm * 64 + (lane & 15)) * 8;
    const int fB = ((lane >> 4) * 128 + wn * 64 + (lane & 15)) * 8;

    f32x4 acc[4][4];
#pragma unroll
    for (int m = 0; m < 4; ++m)
#pragma unroll
        for (int n = 0; n < 4; ++n) acc[m][n] = (f32x4)(0.f);

#define STAGE(buf, t)                                               \
    do {                                                            \
        const uint16_t* ga = Abase + (size_t)(t) * TILE_ELEMS;      \
        const uint16_t* gb = Bbase + (size_t)(t) * TILE_ELEMS;      \
        gl_lds16(ga + off0, &As[buf][off0]);                        \
        gl_lds16(ga + off1, &As[buf][off1]);                        \
        gl_lds16(gb + off0, &Bs[buf][off0]);                        \
        gl_lds16(gb + off1, &Bs[buf][off1]);                        \
    } while (0)

    STAGE(0, 0);
    __syncthreads();

    int cur = 0;
    for (int t = 0; t < KSTEPS; ++t) {
        if (t + 1 < KSTEPS) STAGE(cur ^ 1, t + 1);
        bf16x8 ar[4], br[4];
#pragma unroll
        for (int m = 0; m < 4; ++m) ar[m] = *(const bf16x8*)&As[cur][fA + m * 16 * 8];
#pragma unroll
        for (int n = 0; n < 4; ++n) br[n] = *(const bf16x8*)&Bs[cur][fB + n * 16 * 8];
#pragma unroll
        for (int m = 0; m < 4; ++m)
#pragma unroll
            for (int n = 0; n < 4; ++n)
                acc[m][n] = __builtin_amdgcn_mfma_f32_16x16x32_bf16(
                    ar[m], br[n], acc[m][n], 0, 0, 0);
        __syncthreads();
        cur ^= 1;
    }
#undef STAGE

    // ---- coalesced epilogue: 8 passes x 16 rows through LDS (r16, +9us) ----
    float* Cs = (float*)&As[0][0];
    const int mrow = (lane >> 4) * 4;               // 0,4,8,12
    const int ccol = wn * 64 + (lane & 15);         // col base within tile
    const int srow = tid >> 4;                      // 0..15 (stream row)
    const int scol = (tid & 15) * 4;                // 0..60 (stream col base)

#pragma unroll
    for (int p = 0; p < 8; ++p) {
        __syncthreads();                            // Cs free
        if (wm == (p >> 2)) {
            const int m = p & 3;                    // compile-time (unrolled)
#pragma unroll
            for (int n = 0; n < 4; ++n)
#pragma unroll
                for (int r = 0; r < 4; ++r)
                    Cs[(mrow + r) * 132 + ccol + n * 16] = acc[m][n][r];
        }
        __syncthreads();                            // slab staged
        const int grow = rowTile * BM + p * 16 + srow;
        const float xr = xn[grow];
        float* orow = out + (size_t)grow * C_ROWS;
#pragma unroll
        for (int s = 0; s < 2; ++s) {
            const int c  = scol + s * 64;           // col in tile
            const int gc = colTile * BN + c;
            f32x4 d = *(f32x4*)&Cs[srow * 132 + c];
            f32x4 y4 = *(const f32x4*)&yn[gc];
            f32x4 v;
#pragma unroll
            for (int j = 0; j < 4; ++j)
                v[j] = fmaxf(xr + y4[j] - 2.0f * d[j], 0.f);
            if (gc + 3 < C_ROWS) {
                *(f32x4*)&orow[gc] = v;
            } else {
#pragma unroll
                for (int j = 0; j < 4; ++j)
                    if (gc + j < C_ROWS) orow[gc + j] = v[j];
            }
        }
    }
}

// ---------------- fallback path (round-7 validated) if ws is too small ------
__global__ void row_norms_kernel(const float* __restrict__ x,
                                 float* __restrict__ out,
                                 int rows, int pad_rows) {
    int gid  = blockIdx.x * blockDim.x + threadIdx.x;
    int wid  = gid >> 6;
    int lane = threadIdx.x & 63;
    if (wid >= pad_rows) return;
    float s = 0.f;
    if (wid < rows) {
        const f32x4* rp = (const f32x4*)(x + (size_t)wid * D_DIM);
#pragma unroll
        for (int r = 0; r < D_DIM / 256; ++r) {
            f32x4 v = rp[r * 64 + lane];
            s += v[0]*v[0] + v[1]*v[1] + v[2]*v[2] + v[3]*v[3];
        }
    }
#pragma unroll
    for (int off = 32; off > 0; off >>= 1) s += __shfl_down(s, off, 64);
    if (lane == 0) out[wid] = s;
}

__global__ __launch_bounds__(256, 2)
void dist_gemm_kernel(const float* __restrict__ E,
                      const float* __restrict__ Cc,
                      const float* __restrict__ xn,
                      const float* __restrict__ yn,
                      float* __restrict__ out) {
    __shared__ uint16_t As[4 * 128 * 8];
    __shared__ uint16_t Bs[4 * 128 * 8];
    const int tid  = threadIdx.x;
    const int lane = tid & 63;
    const int wid  = tid >> 6;
    const int wm   = wid >> 1;
    const int wn   = wid & 1;
    const int rowTile = blockIdx.y;
    const int colTile = blockIdx.x;
    const int srow = tid & 127;
    const int sp   = tid >> 7;
    const int ga = rowTile * 128 + srow;
    const int gb = colTile * 128 + srow;
    const float* Arow = E  + (size_t)ga * D_DIM + sp * 16;
    const float* Brow = Cc + (size_t)gb * D_DIM + sp * 16;
    const bool bvalid = (gb < C_ROWS);
    f32x4 acc[4][4];
#pragma unroll
    for (int m = 0; m < 4; ++m)
#pragma unroll
        for (int n = 0; n < 4; ++n) acc[m][n] = (f32x4)(0.f);
    const int fragA_base = (((lane >> 4) * 128) + wm * 64 + (lane & 15)) * 8;
    const int fragB_base = (((lane >> 4) * 128) + wn * 64 + (lane & 15)) * 8;
    const int stA0 = ((sp * 2) * 128 + srow) * 8;
    const int stA1 = ((sp * 2 + 1) * 128 + srow) * 8;
    for (int k0 = 0; k0 < D_DIM; k0 += 32) {
        f32x4 a0 = *(const f32x4*)(Arow + k0);
        f32x4 a1 = *(const f32x4*)(Arow + k0 + 4);
        f32x4 a2 = *(const f32x4*)(Arow + k0 + 8);
        f32x4 a3 = *(const f32x4*)(Arow + k0 + 12);
        f32x4 b0 = (f32x4)(0.f), b1 = (f32x4)(0.f),
              b2 = (f32x4)(0.f), b3 = (f32x4)(0.f);
        if (bvalid) {
            b0 = *(const f32x4*)(Brow + k0);
            b1 = *(const f32x4*)(Brow + k0 + 4);
            b2 = *(const f32x4*)(Brow + k0 + 8);
            b3 = *(const f32x4*)(Brow + k0 + 12);
        }
        u32x4 pa01, pa23, pb01, pb23;
        pa01[0] = pk2bf(a0[0], a0[1]); pa01[1] = pk2bf(a0[2], a0[3]);
        pa01[2] = pk2bf(a1[0], a1[1]); pa01[3] = pk2bf(a1[2], a1[3]);
        pa23[0] = pk2bf(a2[0], a2[1]); pa23[1] = pk2bf(a2[2], a2[3]);
        pa23[2] = pk2bf(a3[0], a3[1]); pa23[3] = pk2bf(a3[2], a3[3]);
        pb01[0] = pk2bf(b0[0], b0[1]); pb01[1] = pk2bf(b0[2], b0[3]);
        pb01[2] = pk2bf(b1[0], b1[1]); pb01[3] = pk2bf(b1[2], b1[3]);
        pb23[0] = pk2bf(b2[0], b2[1]); pb23[1] = pk2bf(b2[2], b2[3]);
        pb23[2] = pk2bf(b3[0], b3[1]); pb23[3] = pk2bf(b3[2], b3[3]);
        __syncthreads();
        *(u32x4*)&As[stA0] = pa01;
        *(u32x4*)&As[stA1] = pa23;
        *(u32x4*)&Bs[stA0] = pb01;
        *(u32x4*)&Bs[stA1] = pb23;
        __syncthreads();
        bf16x8 ar[4], br[4];
#pragma unroll
        for (int m = 0; m < 4; ++m) ar[m] = *(const bf16x8*)&As[fragA_base + m * 16 * 8];
#pragma unroll
        for (int n = 0; n < 4; ++n) br[n] = *(const bf16x8*)&Bs[fragB_base + n * 16 * 8];
#pragma unroll
        for (int m = 0; m < 4; ++m)
#pragma unroll
            for (int n = 0; n < 4; ++n)
                acc[m][n] = __builtin_amdgcn_mfma_f32_16x16x32_bf16(
                    ar[m], br[n], acc[m][n], 0, 0, 0);
    }
    const int orow0 = rowTile * 128 + wm * 64 + ((lane >> 4) * 4);
    const int ocol0 = colTile * 128 + wn * 64 + (lane & 15);
#pragma unroll
    for (int n = 0; n < 4; ++n) {
        int gc = ocol0 + n * 16;
        if (gc >= C_ROWS) continue;
        float ynv = yn[gc];
#pragma unroll
        for (int m = 0; m < 4; ++m) {
            int gr = orow0 + m * 16;
#pragma unroll
            for (int r = 0; r < 4; ++r) {
                float v = xn[gr + r] + ynv - 2.0f * acc[m][n][r];
                out[(size_t)(gr + r) * C_ROWS + gc] = fmaxf(v, 0.f);
            }
        }
    }
}

extern "C" void kernel_launch(void* const* d_in, const int* in_sizes, int n_in,
                              void* d_out, int out_size, void* d_ws, size_t ws_size,
                              hipStream_t stream) {
    const float* E  = (const float*)d_in[0];   // [16384, 1024]
    const float* Cc = (const float*)d_in[1];   // [1000, 1024]
    float* out = (float*)d_out;                // [16384, 1000]

    // ws layout: Et 32MB | Ct 2MB | xn 64KB | yn 4KB  (tiled bf16 images)
    uint16_t* Et = (uint16_t*)d_ws;
    uint16_t* Ct = Et + (size_t)N_ROWS * D_DIM;
    float*    xn = (float*)(Ct + (size_t)C_PAD * D_DIM);
    float*    yn = xn + N_ROWS;
    size_t need = (size_t)((char*)(yn + C_PAD) - (char*)d_ws);

    if (ws_size >= need) {
        convert_norm_both<<<(N_ROWS + C_PAD) / 4, 256, 0, stream>>>(
            E, Et, xn, Cc, Ct, yn);
        dim3 grid(N_ROWS / BM, C_PAD / BN);    // (128, 8)
        dist_gemm2<<<grid, 256, 0, stream>>>(Et, Ct, xn, yn, out);
    } else {
        // fallback: round-7 validated path (needs only ~68 KB ws)
        float* fxn = (float*)d_ws;
        float* fyn = fxn + N_ROWS;
        row_norms_kernel<<<N_ROWS / 4, 256, 0, stream>>>(E,  fxn, N_ROWS, N_ROWS);
        row_norms_kernel<<<C_PAD  / 4, 256, 0, stream>>>(Cc, fyn, C_ROWS, C_PAD);
        dim3 grid(C_PAD / 128, N_ROWS / 128);
        dist_gemm_kernel<<<grid, 256, 0, stream>>>(E, Cc, fxn, fyn, out);
    }
}